// Round 5
// baseline (363.368 us; speedup 1.0000x reference)
//
#include <hip/hip_runtime.h>
#include <stdint.h>

#define N_ROWS 4096
#define Z_DIM  2048
#define TOT    8192           // 2N rows of reps
#define TILE   256
#define BKB    128            // K fp8 bytes per staging round
#define NITER  (Z_DIM / BKB)  // 16
#define NT     (TOT / TILE)   // 32 tile-columns
#define NBLK   (NT * (NT + 1) / 2)   // 528 triangular blocks
#define INV_T  2.0f           // 1/temperature
#define SCL    16.0f          // fp8 pre-scale; logits = acc * INV_T / (SCL*SCL)
#define OPB    (TILE * BKB)   // 32 KiB per operand panel
#define BUFB   (2 * OPB)      // 64 KiB per buffer (A+B)
#define LDSZ   (2 * BUFB)     // 128 KiB double-buffered

typedef __attribute__((ext_vector_type(4))) int   intx4;
typedef __attribute__((ext_vector_type(8))) int   intx8;
typedef __attribute__((ext_vector_type(4))) float floatx4;

#define GLOAD16(g, l)                                                   \
    __builtin_amdgcn_global_load_lds(                                   \
        (const __attribute__((address_space(1))) unsigned int*)(g),     \
        (__attribute__((address_space(3))) unsigned int*)(l), 16, 0, 0)

// ---------------- kernel 1: row-normalize to fp8(e4m3, x16), pos, zero state
__global__ __launch_bounds__(256) void normalize_kernel(
    const float* __restrict__ z1, const float* __restrict__ z2,
    unsigned char* __restrict__ reps, float* __restrict__ pos,
    float* __restrict__ rowsum, int* __restrict__ counter)
{
    const int row  = blockIdx.x;          // 0..4095
    const int tid  = threadIdx.x;         // 0..255, 8 floats each
    const int lane = tid & 63, wave = tid >> 6;

    if (row < TOT / 256) rowsum[row * 256 + tid] = 0.f;   // fold in memset
    if (row == 0 && tid == 0) *counter = 0;

    const float4* p1 = (const float4*)(z1 + (size_t)row * Z_DIM);
    const float4* p2 = (const float4*)(z2 + (size_t)row * Z_DIM);
    float4 x0 = p1[tid * 2], x1 = p1[tid * 2 + 1];
    float4 y0 = p2[tid * 2], y1 = p2[tid * 2 + 1];

    float s1 = x0.x*x0.x + x0.y*x0.y + x0.z*x0.z + x0.w*x0.w
             + x1.x*x1.x + x1.y*x1.y + x1.z*x1.z + x1.w*x1.w;
    float s2 = y0.x*y0.x + y0.y*y0.y + y0.z*y0.z + y0.w*y0.w
             + y1.x*y1.x + y1.y*y1.y + y1.z*y1.z + y1.w*y1.w;
    float dd = x0.x*y0.x + x0.y*y0.y + x0.z*y0.z + x0.w*y0.w
             + x1.x*y1.x + x1.y*y1.y + x1.z*y1.z + x1.w*y1.w;

    #pragma unroll
    for (int m = 1; m < 64; m <<= 1) {
        s1 += __shfl_xor(s1, m);
        s2 += __shfl_xor(s2, m);
        dd += __shfl_xor(dd, m);
    }
    __shared__ float red[3][4];
    if (lane == 0) { red[0][wave] = s1; red[1][wave] = s2; red[2][wave] = dd; }
    __syncthreads();
    s1 = red[0][0] + red[0][1] + red[0][2] + red[0][3];
    s2 = red[1][0] + red[1][1] + red[1][2] + red[1][3];
    dd = red[2][0] + red[2][1] + red[2][2] + red[2][3];

    const float inv1 = rsqrtf(s1), inv2 = rsqrtf(s2);
    if (tid == 0) {
        float p = dd * inv1 * inv2 * INV_T;   // pos in full fp32 precision
        pos[row] = p;
        pos[row + N_ROWS] = p;
    }

    const float a = inv1 * SCL, b = inv2 * SCL;
    unsigned int a0 = 0, a1 = 0, b0 = 0, b1 = 0;
    a0 = __builtin_amdgcn_cvt_pk_fp8_f32(x0.x * a, x0.y * a, a0, false);
    a0 = __builtin_amdgcn_cvt_pk_fp8_f32(x0.z * a, x0.w * a, a0, true);
    a1 = __builtin_amdgcn_cvt_pk_fp8_f32(x1.x * a, x1.y * a, a1, false);
    a1 = __builtin_amdgcn_cvt_pk_fp8_f32(x1.z * a, x1.w * a, a1, true);
    b0 = __builtin_amdgcn_cvt_pk_fp8_f32(y0.x * b, y0.y * b, b0, false);
    b0 = __builtin_amdgcn_cvt_pk_fp8_f32(y0.z * b, y0.w * b, b0, true);
    b1 = __builtin_amdgcn_cvt_pk_fp8_f32(y1.x * b, y1.y * b, b1, false);
    b1 = __builtin_amdgcn_cvt_pk_fp8_f32(y1.z * b, y1.w * b, b1, true);
    uint2 pa = {a0, a1}, pb = {b0, b1};
    *(uint2*)(reps + (size_t)row * Z_DIM + tid * 8) = pa;
    *(uint2*)(reps + (size_t)(N_ROWS + row) * Z_DIM + tid * 8) = pb;
}

// ---------------- kernel 2: triangular S = reps@reps^T, MX-fp8 K=128 --------
// 256x256 tile, 4 waves in 2x2, each wave 128x128 (8x8 grid of 16x16x128
// MFMA, acc=256 VGPR, 1 block/CU). Double-buffered 128 KiB dynamic LDS with
// all-wave prefetch: issue global_load_lds for tile i+1, compute tile i
// (64 MFMA = 2208 cyc >> load latency), ONE barrier — the vmcnt drain is
// pre-satisfied by compute time. Finalize fused via atomic block counter.
// LDS 16B-chunk swizzle slot = kc ^ (row&7) (round-2-verified pattern).
__global__ __launch_bounds__(256, 1) void simclr_gemm(
    const unsigned char* __restrict__ reps, float* __restrict__ rowsum,
    const float* __restrict__ pos, int* __restrict__ counter,
    float* __restrict__ out)
{
    extern __shared__ unsigned char Ld[];   // LDSZ = 128 KiB

    // decode linear block id -> lower-triangle (tr >= tc); bi = tc, bj = tr
    const int t = blockIdx.x;
    int tr = (int)((sqrtf(8.0f * (float)t + 1.0f) - 1.0f) * 0.5f);
    while ((tr + 1) * (tr + 2) / 2 <= t) ++tr;
    while (tr * (tr + 1) / 2 > t) --tr;
    const int bi = t - tr * (tr + 1) / 2;   // <= bj
    const int bj = tr;
    const bool diag = (bi == bj);

    const int tid  = threadIdx.x;
    const int lane = tid & 63, wave = tid >> 6;
    const int wr = wave >> 1, wc = wave & 1;       // 2x2 waves over 256x256
    const int quad = lane >> 4, l16 = lane & 15;
    const int sw   = l16 & 7;                      // read-side XOR swizzle
    const int row0 = bi * TILE, col0 = bj * TILE;

    // staging: 2048 chunks/operand; thread handles chunks q*256+tid, q=0..7.
    // chunk c: row = c>>3 (= q*32 + tid>>3), slot = c&7, global kc = slot^(row&7).
    const int grow = tid >> 3;
    const int gkc  = (tid & 7) ^ (grow & 7);
    const unsigned char* gA0 = reps + (size_t)(row0 + grow) * Z_DIM + gkc * 16;
    const unsigned char* gB0 = reps + (size_t)(col0 + grow) * Z_DIM + gkc * 16;
    const size_t rstep = (size_t)32 * Z_DIM;       // 32 rows per q group

    // prologue: tile 0 -> buffer 0
    {
        unsigned char* dA = Ld + tid * 16;
        unsigned char* dB = dA + OPB;
        #pragma unroll
        for (int q = 0; q < 8; ++q) {
            GLOAD16(gA0 + q * rstep, dA + q * 4096);
            GLOAD16(gB0 + q * rstep, dB + q * 4096);
        }
    }

    floatx4 acc[8][8];
    #pragma unroll
    for (int i = 0; i < 8; ++i)
        #pragma unroll
        for (int j = 0; j < 8; ++j)
            acc[i][j] = floatx4{0.f, 0.f, 0.f, 0.f};

    __syncthreads();                      // prologue loads landed

    for (int i = 0; i < NITER; ++i) {
        if (i + 1 < NITER) {              // prefetch tile i+1 into buf^1
            const size_t ko = (size_t)(i + 1) * BKB;
            unsigned char* dA = Ld + ((i + 1) & 1) * BUFB + tid * 16;
            unsigned char* dB = dA + OPB;
            #pragma unroll
            for (int q = 0; q < 8; ++q) {
                GLOAD16(gA0 + q * rstep + ko, dA + q * 4096);
                GLOAD16(gB0 + q * rstep + ko, dB + q * 4096);
            }
        }
        const unsigned char* Ab = Ld + (i & 1) * BUFB;
        const unsigned char* Bb = Ab + OPB;

        intx8 bfr[8];
        #pragma unroll
        for (int j = 0; j < 8; ++j) {
            const int rb = (wc * 128 + j * 16 + l16) * BKB;
            intx4 lo = *(const intx4*)&Bb[rb + (((quad * 2)     ^ sw) << 4)];
            intx4 hi = *(const intx4*)&Bb[rb + (((quad * 2 + 1) ^ sw) << 4)];
            bfr[j] = intx8{lo[0], lo[1], lo[2], lo[3], hi[0], hi[1], hi[2], hi[3]};
        }
        #pragma unroll
        for (int fi = 0; fi < 8; ++fi) {
            const int ra = (wr * 128 + fi * 16 + l16) * BKB;
            intx4 lo = *(const intx4*)&Ab[ra + (((quad * 2)     ^ sw) << 4)];
            intx4 hi = *(const intx4*)&Ab[ra + (((quad * 2 + 1) ^ sw) << 4)];
            intx8 afr = intx8{lo[0], lo[1], lo[2], lo[3], hi[0], hi[1], hi[2], hi[3]};
            #pragma unroll
            for (int j = 0; j < 8; ++j)
                acc[fi][j] = __builtin_amdgcn_mfma_scale_f32_16x16x128_f8f6f4(
                    afr, bfr[j], acc[fi][j],
                    0, 0,                      // cbsz=fp8(A), blgp=fp8(B)
                    0, 0x7F7F7F7Fu,            // scale_a = 1.0 (E8M0)
                    0, 0x7F7F7F7Fu);           // scale_b = 1.0
        }
        __syncthreads();
    }

    // Epilogue: C/D layout col = lane&15, row = quad*4 + reg.
    // logit = acc * INV_T / SCL^2; |logit| <= 2 so plain exp-sum is safe.
    const float descale = INV_T / (SCL * SCL);   // 1/128
    float scol[8] = {0.f, 0.f, 0.f, 0.f, 0.f, 0.f, 0.f, 0.f};
    #pragma unroll
    for (int fi = 0; fi < 8; ++fi) {
        const int rbase = row0 + wr * 128 + fi * 16 + quad * 4;
        float srow[4] = {0.f, 0.f, 0.f, 0.f};
        #pragma unroll
        for (int j = 0; j < 8; ++j) {
            const int c = col0 + wc * 128 + j * 16 + l16;
            #pragma unroll
            for (int rr = 0; rr < 4; ++rr) {
                float e = __expf(acc[fi][j][rr] * descale);
                if (diag && (rbase + rr == c)) e = 0.f;  // exclude self-sim
                srow[rr] += e;
                scol[j]  += e;
            }
        }
        #pragma unroll
        for (int rr = 0; rr < 4; ++rr) {
            #pragma unroll
            for (int m = 1; m < 16; m <<= 1) srow[rr] += __shfl_xor(srow[rr], m);
        }
        if (l16 == 0) {
            #pragma unroll
            for (int rr = 0; rr < 4; ++rr)
                atomicAdd(&rowsum[rbase + rr], srow[rr]);
        }
    }
    if (!diag) {   // symmetry credit: column sums -> mirrored rows
        #pragma unroll
        for (int j = 0; j < 8; ++j) {
            scol[j] += __shfl_xor(scol[j], 16);
            scol[j] += __shfl_xor(scol[j], 32);
        }
        if (quad == 0) {
            #pragma unroll
            for (int j = 0; j < 8; ++j)
                atomicAdd(&rowsum[col0 + wc * 128 + j * 16 + l16], scol[j]);
        }
    }

    // ---- fused finalize: last block computes mean(log(rowsum) - pos) ----
    __syncthreads();             // all this block's atomics drained (vmcnt)
    __threadfence();             // make them device-visible before counter
    __shared__ int lastBlock;
    if (tid == 0) lastBlock = (atomicAdd(counter, 1) == NBLK - 1) ? 1 : 0;
    __syncthreads();
    if (lastBlock) {
        float s = 0.f;
        for (int rr = tid; rr < TOT; rr += 256) {
            // device-scope atomic read: coherent view of other XCDs' adds
            float rs = atomicAdd(&rowsum[rr], 0.0f);
            s += logf(rs) - pos[rr];
        }
        #pragma unroll
        for (int m = 1; m < 64; m <<= 1) s += __shfl_xor(s, m);
        float* red = (float*)Ld;           // reuse LDS
        if (lane == 0) red[wave] = s;
        __syncthreads();
        if (tid == 0) out[0] = (red[0] + red[1] + red[2] + red[3]) * (1.0f / TOT);
    }
}

extern "C" void kernel_launch(void* const* d_in, const int* in_sizes, int n_in,
                              void* d_out, int out_size, void* d_ws, size_t ws_size,
                              hipStream_t stream)
{
    const float* z1 = (const float*)d_in[0];
    const float* z2 = (const float*)d_in[1];
    float* out = (float*)d_out;

    char* w = (char*)d_ws;
    unsigned char* reps = (unsigned char*)w;                 // 16 MiB fp8 [8192][2048]
    float* pos    = (float*)(w + (size_t)TOT * Z_DIM);       // 32 KiB
    float* rowsum = pos + TOT;                               // 32 KiB
    int*   counter = (int*)(rowsum + TOT);

    // allow 128 KiB dynamic LDS (host-side attribute; not a stream op, so
    // graph-capture-safe; idempotent across calls)
    static int lds_set = 0;  // host-side only; does not affect device work
    hipFuncSetAttribute((const void*)simclr_gemm,
                        hipFuncAttributeMaxDynamicSharedMemorySize, LDSZ);

    normalize_kernel<<<N_ROWS, 256, 0, stream>>>(z1, z2, reps, pos, rowsum, counter);
    simclr_gemm<<<NBLK, 256, LDSZ, stream>>>(reps, rowsum, pos, counter, out);
}

// Round 6
// 181.762 us; speedup vs baseline: 1.9991x; 1.9991x over previous
//
#include <hip/hip_runtime.h>
#include <stdint.h>

#define N_ROWS 4096
#define Z_DIM  2048
#define TOT    8192           // 2N rows of reps
#define TILE   128
#define BKB    128            // K fp8 bytes per staging round
#define NITER  (Z_DIM / BKB)  // 16
#define NT     (TOT / TILE)   // 64 tile-columns
#define NBLK   (NT * (NT + 1) / 2)   // 2080 triangular blocks
#define INV_T  2.0f           // 1/temperature
#define SCL    16.0f          // fp8 pre-scale; logits = acc * INV_T / (SCL*SCL)

typedef __attribute__((ext_vector_type(4))) int   intx4;
typedef __attribute__((ext_vector_type(8))) int   intx8;
typedef __attribute__((ext_vector_type(4))) float floatx4;

#define GLOAD16(g, l)                                                   \
    __builtin_amdgcn_global_load_lds(                                   \
        (const __attribute__((address_space(1))) unsigned int*)(g),     \
        (__attribute__((address_space(3))) unsigned int*)(l), 16, 0, 0)

// ---------------- kernel 1: row-normalize to fp8(e4m3, x16), pos, zero rowsum
__global__ __launch_bounds__(256) void normalize_kernel(
    const float* __restrict__ z1, const float* __restrict__ z2,
    unsigned char* __restrict__ reps, float* __restrict__ pos,
    float* __restrict__ rowsum)
{
    const int row  = blockIdx.x;          // 0..4095
    const int tid  = threadIdx.x;         // 0..255, 8 floats each
    const int lane = tid & 63, wave = tid >> 6;

    if (row < TOT / 256) rowsum[row * 256 + tid] = 0.f;   // fold in memset

    const float4* p1 = (const float4*)(z1 + (size_t)row * Z_DIM);
    const float4* p2 = (const float4*)(z2 + (size_t)row * Z_DIM);
    float4 x0 = p1[tid * 2], x1 = p1[tid * 2 + 1];
    float4 y0 = p2[tid * 2], y1 = p2[tid * 2 + 1];

    float s1 = x0.x*x0.x + x0.y*x0.y + x0.z*x0.z + x0.w*x0.w
             + x1.x*x1.x + x1.y*x1.y + x1.z*x1.z + x1.w*x1.w;
    float s2 = y0.x*y0.x + y0.y*y0.y + y0.z*y0.z + y0.w*y0.w
             + y1.x*y1.x + y1.y*y1.y + y1.z*y1.z + y1.w*y1.w;
    float dd = x0.x*y0.x + x0.y*y0.y + x0.z*y0.z + x0.w*y0.w
             + x1.x*y1.x + x1.y*y1.y + x1.z*y1.z + x1.w*y1.w;

    #pragma unroll
    for (int m = 1; m < 64; m <<= 1) {
        s1 += __shfl_xor(s1, m);
        s2 += __shfl_xor(s2, m);
        dd += __shfl_xor(dd, m);
    }
    __shared__ float red[3][4];
    if (lane == 0) { red[0][wave] = s1; red[1][wave] = s2; red[2][wave] = dd; }
    __syncthreads();
    s1 = red[0][0] + red[0][1] + red[0][2] + red[0][3];
    s2 = red[1][0] + red[1][1] + red[1][2] + red[1][3];
    dd = red[2][0] + red[2][1] + red[2][2] + red[2][3];

    const float inv1 = rsqrtf(s1), inv2 = rsqrtf(s2);
    if (tid == 0) {
        float p = dd * inv1 * inv2 * INV_T;   // pos in full fp32 precision
        pos[row] = p;
        pos[row + N_ROWS] = p;
    }

    const float a = inv1 * SCL, b = inv2 * SCL;
    unsigned int a0 = 0, a1 = 0, b0 = 0, b1 = 0;
    a0 = __builtin_amdgcn_cvt_pk_fp8_f32(x0.x * a, x0.y * a, a0, false);
    a0 = __builtin_amdgcn_cvt_pk_fp8_f32(x0.z * a, x0.w * a, a0, true);
    a1 = __builtin_amdgcn_cvt_pk_fp8_f32(x1.x * a, x1.y * a, a1, false);
    a1 = __builtin_amdgcn_cvt_pk_fp8_f32(x1.z * a, x1.w * a, a1, true);
    b0 = __builtin_amdgcn_cvt_pk_fp8_f32(y0.x * b, y0.y * b, b0, false);
    b0 = __builtin_amdgcn_cvt_pk_fp8_f32(y0.z * b, y0.w * b, b0, true);
    b1 = __builtin_amdgcn_cvt_pk_fp8_f32(y1.x * b, y1.y * b, b1, false);
    b1 = __builtin_amdgcn_cvt_pk_fp8_f32(y1.z * b, y1.w * b, b1, true);
    uint2 pa = {a0, a1}, pb = {b0, b1};
    *(uint2*)(reps + (size_t)row * Z_DIM + tid * 8) = pa;
    *(uint2*)(reps + (size_t)(N_ROWS + row) * Z_DIM + tid * 8) = pb;
}

// ---------------- kernel 2: triangular S = reps@reps^T, MX-fp8 K=128 --------
// Round-3 structure (128x128 tile, 2x2 waves, 4x4 grid of 16x16x128 MFMA,
// acc=64 VGPR/wave) + double-buffered LDS with ONE barrier per iter:
// prefetch tile i+1 into buf^1 is issued BEFORE the 16 MFMAs of tile i, so
// the end-of-iter vmcnt drain is pre-covered by ~550 cyc of MFMA. 64 KiB LDS
// -> 2 blocks/CU for cross-block latency cover.
// LDS 16B-chunk swizzle slot = kc ^ (row&7) (round-2-verified pattern).
__global__ __launch_bounds__(256) void simclr_gemm(
    const unsigned char* __restrict__ reps, float* __restrict__ rowsum)
{
    __shared__ __align__(16) unsigned char L[2][2][TILE * BKB];   // 64 KiB

    // decode linear block id -> lower-triangle (r >= c); bi = c, bj = r
    const int t = blockIdx.x;
    int r = (int)((sqrtf(8.0f * (float)t + 1.0f) - 1.0f) * 0.5f);
    while ((r + 1) * (r + 2) / 2 <= t) ++r;
    while (r * (r + 1) / 2 > t) --r;
    const int bi = t - r * (r + 1) / 2;   // <= bj
    const int bj = r;
    const bool diag = (bi == bj);

    const int tid  = threadIdx.x;
    const int lane = tid & 63, wave = tid >> 6;
    const int wr = wave >> 1, wc = wave & 1;       // 2x2 waves over 128x128
    const int quad = lane >> 4, l16 = lane & 15;
    const int sw   = l16 & 7;                      // read-side XOR swizzle
    const int row0 = bi * TILE, col0 = bj * TILE;

    floatx4 acc[4][4];
    #pragma unroll
    for (int i = 0; i < 4; ++i)
        #pragma unroll
        for (int j = 0; j < 4; ++j)
            acc[i][j] = floatx4{0.f, 0.f, 0.f, 0.f};

    // staging: 1024 chunks of 16B per operand; thread handles chunks tid+q*256.
    // LDS slot c holds global 16B-chunk ((c&7) ^ ((c>>3)&7)) of row c>>3.
    const unsigned char* gA[4]; const unsigned char* gB[4];
    int ldsOff[4];
    #pragma unroll
    for (int q = 0; q < 4; ++q) {
        const int c = q * 256 + tid;
        const int srow = c >> 3, gkc = (c & 7) ^ (srow & 7);
        gA[q] = reps + (size_t)(row0 + srow) * Z_DIM + gkc * 16;
        gB[q] = reps + (size_t)(col0 + srow) * Z_DIM + gkc * 16;
        ldsOff[q] = c * 16;
    }

    // prologue: tile 0 -> buffer 0
    #pragma unroll
    for (int q = 0; q < 4; ++q) GLOAD16(gA[q], &L[0][0][ldsOff[q]]);
    #pragma unroll
    for (int q = 0; q < 4; ++q) GLOAD16(gB[q], &L[0][1][ldsOff[q]]);
    __syncthreads();

    for (int i = 0; i < NITER; ++i) {
        if (i + 1 < NITER) {              // prefetch tile i+1 into buf^1
            const size_t ko = (size_t)(i + 1) * BKB;
            const int buf = (i + 1) & 1;
            #pragma unroll
            for (int q = 0; q < 4; ++q) GLOAD16(gA[q] + ko, &L[buf][0][ldsOff[q]]);
            #pragma unroll
            for (int q = 0; q < 4; ++q) GLOAD16(gB[q] + ko, &L[buf][1][ldsOff[q]]);
        }
        const unsigned char* Ab = &L[i & 1][0][0];
        const unsigned char* Bb = &L[i & 1][1][0];

        // fragment: elem k = quad*32 + j (j over 32 consecutive fp8 bytes)
        intx8 af[4], bf[4];
        #pragma unroll
        for (int fi = 0; fi < 4; ++fi) {
            const int ar = (wr * 64 + fi * 16 + l16) * BKB;
            const int br = (wc * 64 + fi * 16 + l16) * BKB;
            intx4 alo = *(const intx4*)&Ab[ar + (((quad * 2)     ^ sw) << 4)];
            intx4 ahi = *(const intx4*)&Ab[ar + (((quad * 2 + 1) ^ sw) << 4)];
            intx4 blo = *(const intx4*)&Bb[br + (((quad * 2)     ^ sw) << 4)];
            intx4 bhi = *(const intx4*)&Bb[br + (((quad * 2 + 1) ^ sw) << 4)];
            af[fi] = intx8{alo[0], alo[1], alo[2], alo[3], ahi[0], ahi[1], ahi[2], ahi[3]};
            bf[fi] = intx8{blo[0], blo[1], blo[2], blo[3], bhi[0], bhi[1], bhi[2], bhi[3]};
        }
        #pragma unroll
        for (int fi = 0; fi < 4; ++fi)
            #pragma unroll
            for (int j = 0; j < 4; ++j)
                acc[fi][j] = __builtin_amdgcn_mfma_scale_f32_16x16x128_f8f6f4(
                    af[fi], bf[j], acc[fi][j],
                    0, 0,                      // cbsz=fp8(A), blgp=fp8(B)
                    0, 0x7F7F7F7Fu,            // scale_a = 1.0 (E8M0)
                    0, 0x7F7F7F7Fu);           // scale_b = 1.0
        __syncthreads();   // own prefetch vmcnt drained (pre-covered by MFMAs)
    }

    // Epilogue: C/D layout col = lane&15, row = quad*4 + reg.
    // logit = acc * INV_T / SCL^2; |logit| <= 2 so plain exp-sum is safe.
    const float descale = INV_T / (SCL * SCL);   // 1/128
    float scol[4] = {0.f, 0.f, 0.f, 0.f};
    #pragma unroll
    for (int fi = 0; fi < 4; ++fi) {
        const int rbase = row0 + wr * 64 + fi * 16 + quad * 4;
        float srow[4] = {0.f, 0.f, 0.f, 0.f};
        #pragma unroll
        for (int j = 0; j < 4; ++j) {
            const int c = col0 + wc * 64 + j * 16 + l16;
            #pragma unroll
            for (int rr = 0; rr < 4; ++rr) {
                float e = __expf(acc[fi][j][rr] * descale);
                if (diag && (rbase + rr == c)) e = 0.f;  // exclude self-sim
                srow[rr] += e;
                scol[j]  += e;
            }
        }
        #pragma unroll
        for (int rr = 0; rr < 4; ++rr) {
            #pragma unroll
            for (int m = 1; m < 16; m <<= 1) srow[rr] += __shfl_xor(srow[rr], m);
        }
        if (l16 == 0) {
            #pragma unroll
            for (int rr = 0; rr < 4; ++rr)
                atomicAdd(&rowsum[rbase + rr], srow[rr]);
        }
    }
    if (!diag) {   // symmetry credit: column sums -> mirrored rows
        #pragma unroll
        for (int j = 0; j < 4; ++j) {
            scol[j] += __shfl_xor(scol[j], 16);
            scol[j] += __shfl_xor(scol[j], 32);
        }
        if (quad == 0) {
            #pragma unroll
            for (int j = 0; j < 4; ++j)
                atomicAdd(&rowsum[col0 + wc * 64 + j * 16 + l16], scol[j]);
        }
    }
}

// ---------------- kernel 3: mean(log(rowsum) - pos) ----------------
__global__ __launch_bounds__(1024) void finalize_kernel(
    const float* __restrict__ rowsum, const float* __restrict__ pos,
    float* __restrict__ out)
{
    const int tid = threadIdx.x;
    const int lane = tid & 63, wave = tid >> 6;
    float s = 0.f;
    for (int r = tid; r < TOT; r += 1024) s += logf(rowsum[r]) - pos[r];
    #pragma unroll
    for (int m = 1; m < 64; m <<= 1) s += __shfl_xor(s, m);
    __shared__ float red[16];
    if (lane == 0) red[wave] = s;
    __syncthreads();
    if (tid == 0) {
        float t = 0.f;
        #pragma unroll
        for (int w = 0; w < 16; ++w) t += red[w];
        out[0] = t * (1.0f / TOT);
    }
}

extern "C" void kernel_launch(void* const* d_in, const int* in_sizes, int n_in,
                              void* d_out, int out_size, void* d_ws, size_t ws_size,
                              hipStream_t stream)
{
    const float* z1 = (const float*)d_in[0];
    const float* z2 = (const float*)d_in[1];
    float* out = (float*)d_out;

    char* w = (char*)d_ws;
    unsigned char* reps = (unsigned char*)w;                 // 16 MiB fp8 [8192][2048]
    float* pos    = (float*)(w + (size_t)TOT * Z_DIM);       // 32 KiB
    float* rowsum = pos + TOT;                               // 32 KiB

    normalize_kernel<<<N_ROWS, 256, 0, stream>>>(z1, z2, reps, pos, rowsum);
    simclr_gemm<<<NBLK, 256, 0, stream>>>(reps, rowsum);
    finalize_kernel<<<1, 1024, 0, stream>>>(rowsum, pos, out);
}

// Round 7
// 155.653 us; speedup vs baseline: 2.3345x; 1.1677x over previous
//
#include <hip/hip_runtime.h>
#include <stdint.h>

#define N_ROWS 4096
#define Z_DIM  2048
#define TOT    8192           // 2N rows of reps
#define TILE   128
#define RBYTES (Z_DIM / 2)    // 1024 B per fp4 row
#define BKE    128            // K elements per staging round
#define KBYT   (BKE / 2)      // 64 B per row per staging round
#define NITER  (Z_DIM / BKE)  // 16
#define NT     (TOT / TILE)   // 64 tile-columns
#define NBLK   (NT * (NT + 1) / 2)   // 2080 triangular blocks
#define INV_T  2.0f           // 1/temperature
#define SCL4   64.0f          // fp4 pre-scale; logits = acc * INV_T / SCL4^2

typedef __attribute__((ext_vector_type(4))) int   intx4;
typedef __attribute__((ext_vector_type(8))) int   intx8;
typedef __attribute__((ext_vector_type(4))) float floatx4;

#define GLOAD16(g, l)                                                   \
    __builtin_amdgcn_global_load_lds(                                   \
        (const __attribute__((address_space(1))) unsigned int*)(g),     \
        (__attribute__((address_space(3))) unsigned int*)(l), 16, 0, 0)

// branchless f32 -> fp4 e2m1 code (round to nearest level)
// levels: 0,0.5,1,1.5,2,3,4,6 ; thresholds at midpoints
__device__ __forceinline__ unsigned int f2fp4(float v) {
    float a = fabsf(v);
    unsigned int c = (a >= 0.25f) + (a >= 0.75f) + (a >= 1.25f) + (a >= 1.75f)
                   + (a >= 2.5f)  + (a >= 3.5f)  + (a >= 5.0f);
    return c | (v < 0.f ? 8u : 0u);
}

// ---------------- kernel 1: row-normalize to fp4(e2m1, x64), pos, zero rowsum
__global__ __launch_bounds__(256) void normalize_kernel(
    const float* __restrict__ z1, const float* __restrict__ z2,
    unsigned char* __restrict__ reps, float* __restrict__ pos,
    float* __restrict__ rowsum)
{
    const int row  = blockIdx.x;          // 0..4095
    const int tid  = threadIdx.x;         // 0..255, 8 floats each
    const int lane = tid & 63, wave = tid >> 6;

    if (row < TOT / 256) rowsum[row * 256 + tid] = 0.f;   // fold in memset

    const float4* p1 = (const float4*)(z1 + (size_t)row * Z_DIM);
    const float4* p2 = (const float4*)(z2 + (size_t)row * Z_DIM);
    float4 x0 = p1[tid * 2], x1 = p1[tid * 2 + 1];
    float4 y0 = p2[tid * 2], y1 = p2[tid * 2 + 1];

    float s1 = x0.x*x0.x + x0.y*x0.y + x0.z*x0.z + x0.w*x0.w
             + x1.x*x1.x + x1.y*x1.y + x1.z*x1.z + x1.w*x1.w;
    float s2 = y0.x*y0.x + y0.y*y0.y + y0.z*y0.z + y0.w*y0.w
             + y1.x*y1.x + y1.y*y1.y + y1.z*y1.z + y1.w*y1.w;
    float dd = x0.x*y0.x + x0.y*y0.y + x0.z*y0.z + x0.w*y0.w
             + x1.x*y1.x + x1.y*y1.y + x1.z*y1.z + x1.w*y1.w;

    #pragma unroll
    for (int m = 1; m < 64; m <<= 1) {
        s1 += __shfl_xor(s1, m);
        s2 += __shfl_xor(s2, m);
        dd += __shfl_xor(dd, m);
    }
    __shared__ float red[3][4];
    if (lane == 0) { red[0][wave] = s1; red[1][wave] = s2; red[2][wave] = dd; }
    __syncthreads();
    s1 = red[0][0] + red[0][1] + red[0][2] + red[0][3];
    s2 = red[1][0] + red[1][1] + red[1][2] + red[1][3];
    dd = red[2][0] + red[2][1] + red[2][2] + red[2][3];

    const float inv1 = rsqrtf(s1), inv2 = rsqrtf(s2);
    if (tid == 0) {
        float p = dd * inv1 * inv2 * INV_T;   // pos in full fp32 precision
        pos[row] = p;
        pos[row + N_ROWS] = p;
    }

    // fp4 encode of (normalized * 64): sigma ~1.4, range to ~6 (rare clip).
    // elem k -> byte k/2, LOW nibble = even k.
    const float a = inv1 * SCL4, b = inv2 * SCL4;
    unsigned int pa =  f2fp4(x0.x * a)        | (f2fp4(x0.y * a) << 4)
                    | (f2fp4(x0.z * a) << 8)  | (f2fp4(x0.w * a) << 12)
                    | (f2fp4(x1.x * a) << 16) | (f2fp4(x1.y * a) << 20)
                    | (f2fp4(x1.z * a) << 24) | (f2fp4(x1.w * a) << 28);
    unsigned int pb =  f2fp4(y0.x * b)        | (f2fp4(y0.y * b) << 4)
                    | (f2fp4(y0.z * b) << 8)  | (f2fp4(y0.w * b) << 12)
                    | (f2fp4(y1.x * b) << 16) | (f2fp4(y1.y * b) << 20)
                    | (f2fp4(y1.z * b) << 24) | (f2fp4(y1.w * b) << 28);
    *(unsigned int*)(reps + (size_t)row * RBYTES + tid * 4) = pa;
    *(unsigned int*)(reps + (size_t)(N_ROWS + row) * RBYTES + tid * 4) = pb;
}

// ---------------- kernel 2: triangular S = reps@reps^T, MX-fp4 K=128 --------
// R6 structure (128x128 tile, 2x2 waves, 4x4 grid of 16x16x128 f8f6f4 MFMA
// with FMT=fp4, dbuf + prefetch-before-MFMA) but staging bytes HALVED:
// 16 KB/block-iter, LDS 32 KB total -> ~5 blocks/CU of cross-block overlap.
// A-frag: lane holds elems k = quad*32 + j as 32 nibbles = 16 B = 1 b128.
// LDS 16B-chunk swizzle: slot = kc ^ (row&3) (4 chunks per 64 B row).
__global__ __launch_bounds__(256) void simclr_gemm(
    const unsigned char* __restrict__ reps, float* __restrict__ rowsum)
{
    __shared__ __align__(16) unsigned char L[2][2][TILE * KBYT];   // 32 KiB

    // decode linear block id -> lower-triangle (r >= c); bi = c, bj = r
    const int t = blockIdx.x;
    int r = (int)((sqrtf(8.0f * (float)t + 1.0f) - 1.0f) * 0.5f);
    while ((r + 1) * (r + 2) / 2 <= t) ++r;
    while (r * (r + 1) / 2 > t) --r;
    const int bi = t - r * (r + 1) / 2;   // <= bj
    const int bj = r;
    const bool diag = (bi == bj);

    const int tid  = threadIdx.x;
    const int lane = tid & 63, wave = tid >> 6;
    const int wr = wave >> 1, wc = wave & 1;       // 2x2 waves over 128x128
    const int quad = lane >> 4, l16 = lane & 15;
    const int sw   = l16 & 3;                      // read-side XOR swizzle
    const int row0 = bi * TILE, col0 = bj * TILE;

    floatx4 acc[4][4];
    #pragma unroll
    for (int i = 0; i < 4; ++i)
        #pragma unroll
        for (int j = 0; j < 4; ++j)
            acc[i][j] = floatx4{0.f, 0.f, 0.f, 0.f};

    // staging: 512 chunks of 16B per operand (128 rows x 4 chunks); thread
    // handles chunks tid and tid+256. LDS slot c holds global chunk
    // ((c&3) ^ ((c>>2)&3)) of row c>>2.
    const int c0 = tid, c1 = tid + 256;
    const int r0s = c0 >> 2, k0s = (c0 & 3) ^ (r0s & 3);
    const int r1s = c1 >> 2, k1s = (c1 & 3) ^ (r1s & 3);
    const unsigned char* gA0 = reps + (size_t)(row0 + r0s) * RBYTES + k0s * 16;
    const unsigned char* gA1 = reps + (size_t)(row0 + r1s) * RBYTES + k1s * 16;
    const unsigned char* gB0 = reps + (size_t)(col0 + r0s) * RBYTES + k0s * 16;
    const unsigned char* gB1 = reps + (size_t)(col0 + r1s) * RBYTES + k1s * 16;
    const int o0 = c0 * 16, o1 = c1 * 16;

    // prologue: tile 0 -> buffer 0
    GLOAD16(gA0, &L[0][0][o0]);
    GLOAD16(gA1, &L[0][0][o1]);
    GLOAD16(gB0, &L[0][1][o0]);
    GLOAD16(gB1, &L[0][1][o1]);
    __syncthreads();

    for (int i = 0; i < NITER; ++i) {
        if (i + 1 < NITER) {              // prefetch tile i+1 into buf^1
            const size_t ko = (size_t)(i + 1) * KBYT;
            const int buf = (i + 1) & 1;
            GLOAD16(gA0 + ko, &L[buf][0][o0]);
            GLOAD16(gA1 + ko, &L[buf][0][o1]);
            GLOAD16(gB0 + ko, &L[buf][1][o0]);
            GLOAD16(gB1 + ko, &L[buf][1][o1]);
        }
        const unsigned char* Ab = &L[i & 1][0][0];
        const unsigned char* Bb = &L[i & 1][1][0];

        // fragment: 32 fp4 nibbles (elems k=quad*32..+32) = 16 B = 1 b128.
        // FMT=fp4 reads only v[0:3] of the 8-reg operand; upper half zero.
        intx8 af[4], bf[4];
        #pragma unroll
        for (int fi = 0; fi < 4; ++fi) {
            const int ar = (wr * 64 + fi * 16 + l16) * KBYT;
            const int br = (wc * 64 + fi * 16 + l16) * KBYT;
            intx4 av = *(const intx4*)&Ab[ar + ((quad ^ sw) << 4)];
            intx4 bv = *(const intx4*)&Bb[br + ((quad ^ sw) << 4)];
            af[fi] = intx8{av[0], av[1], av[2], av[3], 0, 0, 0, 0};
            bf[fi] = intx8{bv[0], bv[1], bv[2], bv[3], 0, 0, 0, 0};
        }
        #pragma unroll
        for (int fi = 0; fi < 4; ++fi)
            #pragma unroll
            for (int j = 0; j < 4; ++j)
                acc[fi][j] = __builtin_amdgcn_mfma_scale_f32_16x16x128_f8f6f4(
                    af[fi], bf[j], acc[fi][j],
                    4, 4,                      // cbsz=fp4(A), blgp=fp4(B)
                    0, 0x7F7F7F7Fu,            // scale_a = 1.0 (E8M0)
                    0, 0x7F7F7F7Fu);           // scale_b = 1.0
        __syncthreads();
    }

    // Epilogue: C/D layout col = lane&15, row = quad*4 + reg.
    // logit = acc * INV_T / SCL4^2; |logit| <= 2 so plain exp-sum is safe.
    const float descale = INV_T / (SCL4 * SCL4);   // 1/2048
    float scol[4] = {0.f, 0.f, 0.f, 0.f};
    #pragma unroll
    for (int fi = 0; fi < 4; ++fi) {
        const int rbase = row0 + wr * 64 + fi * 16 + quad * 4;
        float srow[4] = {0.f, 0.f, 0.f, 0.f};
        #pragma unroll
        for (int j = 0; j < 4; ++j) {
            const int c = col0 + wc * 64 + j * 16 + l16;
            #pragma unroll
            for (int rr = 0; rr < 4; ++rr) {
                float e = __expf(acc[fi][j][rr] * descale);
                if (diag && (rbase + rr == c)) e = 0.f;  // exclude self-sim
                srow[rr] += e;
                scol[j]  += e;
            }
        }
        #pragma unroll
        for (int rr = 0; rr < 4; ++rr) {
            #pragma unroll
            for (int m = 1; m < 16; m <<= 1) srow[rr] += __shfl_xor(srow[rr], m);
        }
        if (l16 == 0) {
            #pragma unroll
            for (int rr = 0; rr < 4; ++rr)
                atomicAdd(&rowsum[rbase + rr], srow[rr]);
        }
    }
    if (!diag) {   // symmetry credit: column sums -> mirrored rows
        #pragma unroll
        for (int j = 0; j < 4; ++j) {
            scol[j] += __shfl_xor(scol[j], 16);
            scol[j] += __shfl_xor(scol[j], 32);
        }
        if (quad == 0) {
            #pragma unroll
            for (int j = 0; j < 4; ++j)
                atomicAdd(&rowsum[col0 + wc * 64 + j * 16 + l16], scol[j]);
        }
    }
}

// ---------------- kernel 3: mean(log(rowsum) - pos) ----------------
__global__ __launch_bounds__(1024) void finalize_kernel(
    const float* __restrict__ rowsum, const float* __restrict__ pos,
    float* __restrict__ out)
{
    const int tid = threadIdx.x;
    const int lane = tid & 63, wave = tid >> 6;
    float s = 0.f;
    for (int r = tid; r < TOT; r += 1024) s += logf(rowsum[r]) - pos[r];
    #pragma unroll
    for (int m = 1; m < 64; m <<= 1) s += __shfl_xor(s, m);
    __shared__ float red[16];
    if (lane == 0) red[wave] = s;
    __syncthreads();
    if (tid == 0) {
        float t = 0.f;
        #pragma unroll
        for (int w = 0; w < 16; ++w) t += red[w];
        out[0] = t * (1.0f / TOT);
    }
}

extern "C" void kernel_launch(void* const* d_in, const int* in_sizes, int n_in,
                              void* d_out, int out_size, void* d_ws, size_t ws_size,
                              hipStream_t stream)
{
    const float* z1 = (const float*)d_in[0];
    const float* z2 = (const float*)d_in[1];
    float* out = (float*)d_out;

    char* w = (char*)d_ws;
    unsigned char* reps = (unsigned char*)w;                 // 8 MiB fp4 [8192][1024B]
    float* pos    = (float*)(w + (size_t)TOT * RBYTES);      // 32 KiB
    float* rowsum = pos + TOT;                               // 32 KiB

    normalize_kernel<<<N_ROWS, 256, 0, stream>>>(z1, z2, reps, pos, rowsum);
    simclr_gemm<<<NBLK, 256, 0, stream>>>(reps, rowsum);
    finalize_kernel<<<1, 1024, 0, stream>>>(rowsum, pos, out);
}